// Round 1
// baseline (763.648 us; speedup 1.0000x reference)
//
#include <hip/hip_runtime.h>
#include <stdint.h>

#define NB        16
#define IN_BITS   1024
#define N_IN      2048
#define N_ST      1024
#define N_OUT     512
#define TBL       65536
#define MAX_ITERS 4

// Gather 16 bits (bytes 0/1) from LDS via a 16-int connection row, form address.
__device__ __forceinline__ int gather_addr(const uint8_t* sb, const int* __restrict__ c) {
    const int4* c4 = (const int4*)c;          // conn rows are 64 B, 16 B aligned
    int4 a = c4[0], b = c4[1], cc = c4[2], d = c4[3];
    int addr = 0;
    addr |= (int)sb[a.x]  << 0;
    addr |= (int)sb[a.y]  << 1;
    addr |= (int)sb[a.z]  << 2;
    addr |= (int)sb[a.w]  << 3;
    addr |= (int)sb[b.x]  << 4;
    addr |= (int)sb[b.y]  << 5;
    addr |= (int)sb[b.z]  << 6;
    addr |= (int)sb[b.w]  << 7;
    addr |= (int)sb[cc.x] << 8;
    addr |= (int)sb[cc.y] << 9;
    addr |= (int)sb[cc.z] << 10;
    addr |= (int)sb[cc.w] << 11;
    addr |= (int)sb[d.x]  << 12;
    addr |= (int)sb[d.y]  << 13;
    addr |= (int)sb[d.z]  << 14;
    addr |= (int)sb[d.w]  << 15;
    return addr;
}

__global__ __launch_bounds__(1024)
void ram_multistep_kernel(const int*   __restrict__ x,
                          const int*   __restrict__ conn_in,
                          const int*   __restrict__ conn_state,
                          const int*   __restrict__ conn_out,
                          const float* __restrict__ mem_in,
                          const float* __restrict__ mem_state,
                          const float* __restrict__ mem_out,
                          float*       __restrict__ out)
{
    __shared__ uint8_t xb[IN_BITS];          // input bit vector for this batch
    __shared__ uint8_t bits[N_IN + N_ST];    // [0,2048): in_bits, [2048,3072): state_bits

    const int b   = blockIdx.x;
    const int tid = threadIdx.x;

    // Stage x bits into LDS; zero-init state bits.
    if (tid < IN_BITS) xb[tid] = (uint8_t)x[b * IN_BITS + tid];
    if (tid < N_ST)    bits[N_IN + tid] = 0;
    __syncthreads();

    // Phase 1: in-layer lookups -> in_bits (2048 neurons, 2 per thread).
    #pragma unroll
    for (int n = tid; n < N_IN; n += 1024) {
        int addr = gather_addr(xb, conn_in + n * NB);
        float v  = mem_in[(size_t)n * TBL + (size_t)addr];
        bits[n]  = (v > 0.5f) ? 1 : 0;
    }
    __syncthreads();

    // Phase 2: 4 state iterations (1024 neurons, 1 per thread).
    for (int it = 0; it < MAX_ITERS; ++it) {
        uint8_t nbit = 0;
        if (tid < N_ST) {
            int addr = gather_addr(bits, conn_state + tid * NB);
            float v  = mem_state[(size_t)tid * TBL + (size_t)addr];
            nbit     = (v > 0.5f) ? 1 : 0;
        }
        __syncthreads();                 // all reads of old state done
        if (tid < N_ST) bits[N_IN + tid] = nbit;
        __syncthreads();                 // new state visible
    }

    // Phase 3: out lookups (only the final iteration's out_vals survive).
    if (tid < N_OUT) {
        int addr = gather_addr(bits, conn_out + tid * NB);
        out[b * N_OUT + tid] = mem_out[(size_t)tid * TBL + (size_t)addr];
    }
}

extern "C" void kernel_launch(void* const* d_in, const int* in_sizes, int n_in,
                              void* d_out, int out_size, void* d_ws, size_t ws_size,
                              hipStream_t stream) {
    const int*   x          = (const int*)  d_in[0];
    const int*   conn_in    = (const int*)  d_in[1];
    const int*   conn_state = (const int*)  d_in[2];
    const int*   conn_out   = (const int*)  d_in[3];
    const float* mem_in     = (const float*)d_in[4];
    const float* mem_state  = (const float*)d_in[5];
    const float* mem_out    = (const float*)d_in[6];
    float*       out        = (float*)d_out;

    const int B = in_sizes[0] / IN_BITS;   // 256

    hipLaunchKernelGGL(ram_multistep_kernel, dim3(B), dim3(1024), 0, stream,
                       x, conn_in, conn_state, conn_out,
                       mem_in, mem_state, mem_out, out);
}